// Round 11
// baseline (196.033 us; speedup 1.0000x reference)
//
#include <hip/hip_runtime.h>
#include <cstdint>
#include <cstddef>

// Problem constants: b=2, s=2048, d_model=1024, heads=16, head_dim=64
#define NB 2
#define NS 2048
#define ND 1024
#define NH 16
#define HD 64
#define ROWS 4096      // NB*NS
#define E3 3072        // 3*ND

using bf16 = __bf16;
typedef __attribute__((ext_vector_type(4))) __bf16 bf16x4;
typedef __attribute__((ext_vector_type(8))) __bf16 bf16x8;
typedef __attribute__((ext_vector_type(4))) float f32x4;

__device__ __forceinline__ f32x4 mfma16(bf16x8 a, bf16x8 b, f32x4 c) {
    return __builtin_amdgcn_mfma_f32_16x16x32_bf16(a, b, c, 0, 0, 0);
}

__device__ __forceinline__ void gll16(const bf16* src, bf16* lds) {
    __builtin_amdgcn_global_load_lds(
        (const __attribute__((address_space(1))) void*)src,
        (__attribute__((address_space(3))) void*)lds, 16, 0, 0);
}

// ---------------- fused prep: weight cast | rmsnorm | rope table (independent) ----------------
__global__ __launch_bounds__(256) void prep(const float* __restrict__ qkv_w,
                                            const float* __restrict__ proj_w,
                                            const float* __restrict__ x,
                                            const float* __restrict__ norm_w,
                                            bf16* __restrict__ wq,
                                            bf16* __restrict__ xn,
                                            float4* __restrict__ tab) {
    __shared__ float wsum[4];
    int bid = blockIdx.x;
    int tid = threadIdx.x;
    if (bid < 4096) {                  // weight cast: 4M elems, 4/thread
        const int n1 = E3 * ND;
        int i = (bid * 256 + tid) * 4;
        const float* src = (i < n1) ? (qkv_w + i) : (proj_w + (i - n1));
        float4 v = *(const float4*)src;
        bf16x4 o;
        o[0] = (bf16)v.x; o[1] = (bf16)v.y; o[2] = (bf16)v.z; o[3] = (bf16)v.w;
        *(bf16x4*)(wq + i) = o;
    } else if (bid < 8192) {           // RMSNorm+cast: one block per row
        int row = bid - 4096;
        const float* xr = x + (size_t)row * ND;
        float4 v = ((const float4*)xr)[tid];
        float ss = v.x*v.x + v.y*v.y + v.z*v.z + v.w*v.w;
        #pragma unroll
        for (int m = 32; m >= 1; m >>= 1) ss += __shfl_xor(ss, m);
        if ((tid & 63) == 0) wsum[tid >> 6] = ss;
        __syncthreads();
        float total = wsum[0] + wsum[1] + wsum[2] + wsum[3];
        float scale = rsqrtf(total * (1.0f / ND) + 1e-6f);
        float4 wv = ((const float4*)norm_w)[tid];
        bf16x4 o;
        o[0] = (bf16)(v.x * scale * wv.x);
        o[1] = (bf16)(v.y * scale * wv.y);
        o[2] = (bf16)(v.z * scale * wv.z);
        o[3] = (bf16)(v.w * scale * wv.w);
        ((bf16x4*)(xn + (size_t)row * ND))[tid] = o;
    } else {                           // rope table: tab[s*16+j]
        int idx = (bid - 8192) * 256 + tid;
        int s = idx >> 4, j = idx & 15;
        float f0 = powf(10000.0f, -(float)j * (1.0f / 32.0f));
        float f1 = powf(10000.0f, -(float)(j + 16) * (1.0f / 32.0f));
        float sn0, c0, sn1, c1;
        sincosf((float)s * f0, &sn0, &c0);
        sincosf((float)s * f1, &sn1, &c1);
        tab[idx] = make_float4(c0, sn0, c1, sn1);
    }
}

// ---------------- QKV GEMM, BK=64: half the barriers of BK=32 ----------------
// LDS rows are 64 elems (8 x 16B chunks); chunk c of row r stored at c^(r&7) to kill
// the 16-way ds_read_b128 conflict a 128B stride would cause. Swizzle baked into the
// staging SOURCE (DMA dest is fixed base+lane*16). Epilogues: V frag-major (R8),
// Q/K LDS-transpose->coalesced (R10), both verified.
__global__ __launch_bounds__(256) void gemm_qkv_rope(const bf16* __restrict__ A,
                                                     const bf16* __restrict__ Bm,
                                                     const float* __restrict__ bias,
                                                     const float4* __restrict__ tab,
                                                     bf16* __restrict__ Qb,
                                                     bf16* __restrict__ Kb,
                                                     bf16* __restrict__ Vf) {
    const int K = ND;
    __shared__ bf16 smem[16384];       // Asm[0:8192) | Bsm[8192:16384), 32KB
    bf16* Asm = smem;
    bf16* Bsm = smem + 8192;
    const int tid = threadIdx.x;
    const int wave = tid >> 6, lane = tid & 63;
    const int quad = lane >> 4, l15 = lane & 15;
    const int row0 = blockIdx.x * 128, col0 = blockIdx.y * 128;
    const int wr = (wave >> 1) * 64, wc = (wave & 1) * 64;
    const int x7 = l15 & 7;

    // staging: round i covers rows [i*32,i*32+32); wave stages 8 rows of 64
    const int sR = lane >> 3;               // 0..7
    const int sC = (lane & 7) ^ sR;         // swizzled source chunk
    const bf16* sA = A + (size_t)(row0 + wave * 8 + sR) * K + sC * 8;
    const bf16* sB = Bm + (size_t)(col0 + wave * 8 + sR) * K + sC * 8;

    f32x4 acc[4][4] = {};

    for (int k0 = 0; k0 < K; k0 += 64) {
        #pragma unroll
        for (int i = 0; i < 4; ++i) {
            gll16(sA + (size_t)(i * 32) * K + k0, Asm + (i * 32 + wave * 8) * 64);
            gll16(sB + (size_t)(i * 32) * K + k0, Bsm + (i * 32 + wave * 8) * 64);
        }
        __syncthreads();
        #pragma unroll
        for (int kk = 0; kk < 2; ++kk) {
            bf16x8 af[4], bff[4];
            #pragma unroll
            for (int t = 0; t < 4; ++t) {
                af[t]  = *(const bf16x8*)(Asm + (wr + t * 16 + l15) * 64 + (((kk * 4 + quad) ^ x7) * 8));
                bff[t] = *(const bf16x8*)(Bsm + (wc + t * 16 + l15) * 64 + (((kk * 4 + quad) ^ x7) * 8));
            }
            #pragma unroll
            for (int mt = 0; mt < 4; ++mt)
                #pragma unroll
                for (int nt = 0; nt < 4; ++nt)
                    acc[mt][nt] = mfma16(af[mt], bff[nt], acc[mt][nt]);
        }
        __syncthreads();
    }

    float bb[4];
    #pragma unroll
    for (int nt = 0; nt < 4; ++nt) bb[nt] = bias[col0 + wc + nt * 16 + l15];

    const int region = col0 >> 10;   // 0=Q, 1=K, 2=V
    if (region == 2) {
        const int cv = col0 - 2048 + wc;
        const int h = cv >> 6;
        const int b = row0 >> 11;
        const int sloc = row0 & (NS - 1);
        const int kg0 = (sloc + wr) >> 5;
        bf16* vh = Vf + (size_t)(b * NH + h) * 131072;   // 64 kg * 4 nt * 512
        #pragma unroll
        for (int Gw = 0; Gw < 2; ++Gw) {
            #pragma unroll
            for (int nt = 0; nt < 4; ++nt) {
                bf16x8 vf8;
                #pragma unroll
                for (int r = 0; r < 4; ++r) {
                    vf8[r]     = (bf16)(acc[2 * Gw][nt][r] + bb[nt]);
                    vf8[4 + r] = (bf16)(acc[2 * Gw + 1][nt][r] + bb[nt]);
                }
                *(bf16x8*)(vh + ((size_t)(kg0 + Gw) * 4 + nt) * 512 + lane * 8) = vf8;
            }
        }
    } else {
        const float scale = (region == 0) ? 0.125f : 1.0f;
        bf16* Ob = (region == 0) ? Qb : Kb;
        const int h = ((col0 + wc) & 1023) >> 6;
        bf16* ep = smem + wave * 2048;         // per-wave 32x64 transpose tile
        #pragma unroll
        for (int p = 0; p < 2; ++p) {
            #pragma unroll
            for (int mtl = 0; mtl < 2; ++mtl) {
                const int mt = p * 2 + mtl;
                #pragma unroll
                for (int r = 0; r < 4; ++r) {
                    int row = row0 + wr + mt * 16 + quad * 4 + r;
                    int s = row & (NS - 1);
                    float4 cs = tab[s * 16 + l15];
                    #pragma unroll
                    for (int nt = 0; nt < 4; ++nt) {
                        float v  = acc[mt][nt][r] + bb[nt];
                        float vp = acc[mt][nt ^ 2][r] + bb[nt ^ 2];
                        float cc = (nt & 1) ? cs.z : cs.x;
                        float ss = (nt & 1) ? cs.w : cs.y;
                        float res = (nt < 2) ? (v * cc - vp * ss) : (v * cc + vp * ss);
                        ep[(mtl * 16 + quad * 4 + r) * 64 + nt * 16 + l15] = (bf16)(res * scale);
                    }
                }
            }
            asm volatile("s_waitcnt lgkmcnt(0)" ::: "memory");
            const int rowp = row0 + wr + p * 32;
            const int b = rowp >> 11;
            const int s0p = rowp & (NS - 1);
            bf16* gbase = Ob + ((size_t)(b * NH + h) * NS + s0p + (lane >> 3)) * 64 + (lane & 7) * 8;
            const bf16* lbase = ep + (lane >> 3) * 64 + (lane & 7) * 8;
            #pragma unroll
            for (int i = 0; i < 4; ++i) {
                bf16x8 v8 = *(const bf16x8*)(lbase + i * 512);
                *(bf16x8*)(gbase + (size_t)i * 512) = v8;
            }
            asm volatile("s_waitcnt lgkmcnt(0)" ::: "memory");
        }
    }
}

// ---------------- proj GEMM, BK=64, 128x64 tile: C = A @ B^T + bias, fp32 out ----------------
__global__ __launch_bounds__(256) void gemm_proj(const bf16* __restrict__ A,
                                                 const bf16* __restrict__ Bm,
                                                 const float* __restrict__ bias,
                                                 float* __restrict__ C) {
    __shared__ bf16 Asm[8192];   // 128 x 64
    __shared__ bf16 Bsm[4096];   // 64 x 64
    const int tid = threadIdx.x;
    const int wave = tid >> 6, lane = tid & 63;
    const int quad = lane >> 4, l15 = lane & 15;
    const int row0 = blockIdx.x * 128, col0 = blockIdx.y * 64;
    const int wr = (wave >> 1) * 64, wc = (wave & 1) * 32;
    const int x7 = l15 & 7;

    const int sR = lane >> 3;
    const int sC = (lane & 7) ^ sR;
    const bf16* sA = A + (size_t)(row0 + wave * 8 + sR) * ND + sC * 8;
    const bf16* sB = Bm + (size_t)(col0 + wave * 8 + sR) * ND + sC * 8;

    f32x4 acc[4][2] = {};

    for (int k0 = 0; k0 < ND; k0 += 64) {
        #pragma unroll
        for (int i = 0; i < 4; ++i)
            gll16(sA + (size_t)(i * 32) * ND + k0, Asm + (i * 32 + wave * 8) * 64);
        #pragma unroll
        for (int i = 0; i < 2; ++i)
            gll16(sB + (size_t)(i * 32) * ND + k0, Bsm + (i * 32 + wave * 8) * 64);
        __syncthreads();
        #pragma unroll
        for (int kk = 0; kk < 2; ++kk) {
            bf16x8 af[4], bff[2];
            #pragma unroll
            for (int t = 0; t < 4; ++t)
                af[t] = *(const bf16x8*)(Asm + (wr + t * 16 + l15) * 64 + (((kk * 4 + quad) ^ x7) * 8));
            #pragma unroll
            for (int t = 0; t < 2; ++t)
                bff[t] = *(const bf16x8*)(Bsm + (wc + t * 16 + l15) * 64 + (((kk * 4 + quad) ^ x7) * 8));
            #pragma unroll
            for (int mt = 0; mt < 4; ++mt)
                #pragma unroll
                for (int nt = 0; nt < 2; ++nt)
                    acc[mt][nt] = mfma16(af[mt], bff[nt], acc[mt][nt]);
        }
        __syncthreads();
    }

    #pragma unroll
    for (int nt = 0; nt < 2; ++nt) {
        int col = col0 + wc + nt * 16 + l15;
        float bv = bias[col];
        #pragma unroll
        for (int mt = 0; mt < 4; ++mt) {
            int row = row0 + wr + mt * 16 + quad * 4;
            #pragma unroll
            for (int r = 0; r < 4; ++r)
                C[(size_t)(row + r) * ND + col] = acc[mt][nt][r] + bv;
        }
    }
}

// ---------------- flash attention v9 (unchanged from R10): frag-major V, dbuf staging ----------------
__global__ __launch_bounds__(256) void attn(const bf16* __restrict__ Q,
                                            const bf16* __restrict__ K,
                                            const bf16* __restrict__ Vf,
                                            bf16* __restrict__ Y) {
    __shared__ bf16 Ksm[2][8192];
    __shared__ bf16 Vsm[2][8192];
    int bid = blockIdx.x;
    int g = bid >> 5;
    int bh = bid & 31;
    int qt = (g < 8) ? (15 - g) : (g - 8);
    int tid = threadIdx.x;
    int wave = tid >> 6, lane = tid & 63;
    int quad = lane >> 4, l15 = lane & 15;
    int q0 = qt * 128 + wave * 32;
    const bf16* Qh = Q + (size_t)bh * NS * 64;
    const bf16* Kh = K + (size_t)bh * NS * 64;
    const float NEG_INF = -__builtin_inff();

    const int krow = wave * 8 + (lane >> 3);
    const int ksx  = (lane & 7) ^ (krow & 7);
    const bf16* sK = Kh + (size_t)krow * 64 + ksx * 8;
    const bf16* sV = Vf + (size_t)bh * 131072 + wave * 2048 + lane * 8;

    const bf16* pk0 = &Ksm[0][l15 * 64 + ((quad) ^ (l15 & 7)) * 8];
    const bf16* pk1 = &Ksm[0][l15 * 64 + ((4 + quad) ^ (l15 & 7)) * 8];
    const bf16* pvf = &Vsm[0][lane * 8];

    bf16x8 bq[2][2];
    #pragma unroll
    for (int t = 0; t < 2; ++t)
        #pragma unroll
        for (int hh = 0; hh < 2; ++hh)
            bq[t][hh] = *(const bf16x8*)(Qh + (size_t)(q0 + t * 16 + l15) * 64 + hh * 32 + quad * 8);

    f32x4 o[2][4] = {};
    float lsum[2] = {0.f, 0.f};

    auto stage = [&](int c, int par) {
        const int kb = c * 128;
        bf16* dK = &Ksm[par][wave * 512];
        bf16* dV = &Vsm[par][wave * 2048];
        #pragma unroll
        for (int i = 0; i < 4; ++i)
            gll16(sK + (size_t)(kb + i * 32) * 64, dK + i * 2048);
        #pragma unroll
        for (int nt = 0; nt < 4; ++nt)
            gll16(sV + (size_t)(kb >> 5) * 2048 + nt * 512, dV + nt * 512);
    };

    auto compute = [&](int cc, int par) {
        const int kb = cc * 128;
        const int pb = par * 8192;
        #pragma unroll
        for (int ksub = 0; ksub < 4; ++ksub) {
            const int kbs = kb + ksub * 32;
            if (kbs <= q0) {
                bf16x8 ak00 = *(const bf16x8*)(pk0 + pb + ksub * 2048);
                bf16x8 ak01 = *(const bf16x8*)(pk1 + pb + ksub * 2048);
                bf16x8 ak10 = *(const bf16x8*)(pk0 + pb + ksub * 2048 + 1024);
                bf16x8 ak11 = *(const bf16x8*)(pk1 + pb + ksub * 2048 + 1024);
                bf16x8 vf0 = *(const bf16x8*)(pvf + pb + ksub * 2048);
                bf16x8 vf1 = *(const bf16x8*)(pvf + pb + ksub * 2048 + 512);
                bf16x8 vf2 = *(const bf16x8*)(pvf + pb + ksub * 2048 + 1024);
                bf16x8 vf3 = *(const bf16x8*)(pvf + pb + ksub * 2048 + 1536);
                const bool masked = (kbs == q0);
                #pragma unroll
                for (int t = 0; t < 2; ++t) {
                    f32x4 sh0 = {}, sh1 = {};
                    sh0 = mfma16(ak00, bq[t][0], sh0);
                    sh0 = mfma16(ak01, bq[t][1], sh0);
                    sh1 = mfma16(ak10, bq[t][0], sh1);
                    sh1 = mfma16(ak11, bq[t][1], sh1);
                    if (masked) {
                        int qy = q0 + t * 16 + l15;
                        #pragma unroll
                        for (int r = 0; r < 4; ++r) {
                            if (kbs + quad * 4 + r > qy)      sh0[r] = NEG_INF;
                            if (kbs + 16 + quad * 4 + r > qy) sh1[r] = NEG_INF;
                        }
                    }
                    bf16x8 pa;
                    float ls = 0.f;
                    #pragma unroll
                    for (int j = 0; j < 4; ++j) {
                        float p0 = __expf(sh0[j]);
                        float p1 = __expf(sh1[j]);
                        ls += p0 + p1;
                        pa[j] = (bf16)p0;
                        pa[4 + j] = (bf16)p1;
                    }
                    lsum[t] += ls;
                    o[t][0] = mfma16(pa, vf0, o[t][0]);
                    o[t][1] = mfma16(pa, vf1, o[t][1]);
                    o[t][2] = mfma16(pa, vf2, o[t][2]);
                    o[t][3] = mfma16(pa, vf3, o[t][3]);
                }
            }
        }
    };

    const int ncb = qt + 1;
    stage(0, 0);
    __syncthreads();
    for (int c = 0; c < ncb; ++c) {
        const int par = c & 1;
        if (c + 1 < ncb) stage(c + 1, par ^ 1);
        compute(c, par);
        __syncthreads();
    }

    int b = bh >> 4, h = bh & 15;
    bf16* ep = &Ksm[0][wave * 2048];
    #pragma unroll
    for (int t = 0; t < 2; ++t) {
        float red = lsum[t];
        red += __shfl_xor(red, 16);
        red += __shfl_xor(red, 32);
        #pragma unroll
        for (int r = 0; r < 4; ++r) {
            float il = 1.0f / __shfl(red, quad * 4 + r);
            #pragma unroll
            for (int nt = 0; nt < 4; ++nt)
                ep[(t * 16 + quad * 4 + r) * 64 + nt * 16 + l15] = (bf16)(o[t][nt][r] * il);
        }
    }
    asm volatile("s_waitcnt lgkmcnt(0)" ::: "memory");
    bf16* gbase = Y + ((size_t)(b * NS + q0 + (lane >> 3)) << 10) + h * 64 + (lane & 7) * 8;
    const bf16* lbase = ep + (lane >> 3) * 64 + (lane & 7) * 8;
    #pragma unroll
    for (int i = 0; i < 4; ++i) {
        bf16x8 v8 = *(const bf16x8*)(lbase + i * 512);
        *(bf16x8*)(gbase + ((size_t)i * 8 << 10)) = v8;
    }
}

// ---------------- host launch ----------------
extern "C" void kernel_launch(void* const* d_in, const int* in_sizes, int n_in,
                              void* d_out, int out_size, void* d_ws, size_t ws_size,
                              hipStream_t stream) {
    const float* x      = (const float*)d_in[0];
    const float* norm_w = (const float*)d_in[1];
    const float* qkv_w  = (const float*)d_in[2];
    const float* qkv_b  = (const float*)d_in[3];
    const float* proj_w = (const float*)d_in[4];
    const float* proj_b = (const float*)d_in[5];
    float* out = (float*)d_out;

    char* ws = (char*)d_ws;
    size_t off = 0;
    bf16* xn    = (bf16*)(ws + off); off += (size_t)ROWS * ND * 2;
    bf16* wq    = (bf16*)(ws + off); off += (size_t)E3 * ND * 2;
    bf16* wp    = (bf16*)(ws + off); off += (size_t)ND * ND * 2;   // contiguous after wq
    bf16* Qb    = (bf16*)(ws + off); off += (size_t)NB * NH * NS * HD * 2;
    bf16* Kb    = (bf16*)(ws + off); off += (size_t)NB * NH * NS * HD * 2;
    bf16* Vfrag = (bf16*)(ws + off); off += (size_t)NB * NH * HD * NS * 2;
    bf16* Y     = (bf16*)(ws + off); off += (size_t)ROWS * ND * 2;
    float4* tab = (float4*)(ws + off); off += (size_t)NS * 16 * sizeof(float4);

    prep<<<8320, 256, 0, stream>>>(qkv_w, proj_w, x, norm_w, wq, xn, tab);
    gemm_qkv_rope<<<dim3(ROWS / 128, E3 / 128), 256, 0, stream>>>(xn, wq, qkv_b, tab, Qb, Kb, Vfrag);
    attn<<<NB * NH * (NS / 128), 256, 0, stream>>>(Qb, Kb, Vfrag, Y);
    gemm_proj<<<dim3(ROWS / 128, ND / 64), 256, 0, stream>>>(Y, wp, proj_b, out);
}

// Round 12
// 195.286 us; speedup vs baseline: 1.0038x; 1.0038x over previous
//
#include <hip/hip_runtime.h>
#include <cstdint>
#include <cstddef>

// Problem constants: b=2, s=2048, d_model=1024, heads=16, head_dim=64
#define NB 2
#define NS 2048
#define ND 1024
#define NH 16
#define HD 64
#define ROWS 4096      // NB*NS
#define E3 3072        // 3*ND

using bf16 = __bf16;
typedef __attribute__((ext_vector_type(4))) __bf16 bf16x4;
typedef __attribute__((ext_vector_type(8))) __bf16 bf16x8;
typedef __attribute__((ext_vector_type(4))) float f32x4;

__device__ __forceinline__ f32x4 mfma16(bf16x8 a, bf16x8 b, f32x4 c) {
    return __builtin_amdgcn_mfma_f32_16x16x32_bf16(a, b, c, 0, 0, 0);
}

__device__ __forceinline__ void gll16(const bf16* src, bf16* lds) {
    __builtin_amdgcn_global_load_lds(
        (const __attribute__((address_space(1))) void*)src,
        (__attribute__((address_space(3))) void*)lds, 16, 0, 0);
}

// ---------------- fused prep: weight cast | rmsnorm | rope table (independent) ----------------
__global__ __launch_bounds__(256) void prep(const float* __restrict__ qkv_w,
                                            const float* __restrict__ proj_w,
                                            const float* __restrict__ x,
                                            const float* __restrict__ norm_w,
                                            bf16* __restrict__ wq,
                                            bf16* __restrict__ xn,
                                            float4* __restrict__ tab) {
    __shared__ float wsum[4];
    int bid = blockIdx.x;
    int tid = threadIdx.x;
    if (bid < 4096) {                  // weight cast: 4M elems, 4/thread
        const int n1 = E3 * ND;
        int i = (bid * 256 + tid) * 4;
        const float* src = (i < n1) ? (qkv_w + i) : (proj_w + (i - n1));
        float4 v = *(const float4*)src;
        bf16x4 o;
        o[0] = (bf16)v.x; o[1] = (bf16)v.y; o[2] = (bf16)v.z; o[3] = (bf16)v.w;
        *(bf16x4*)(wq + i) = o;
    } else if (bid < 8192) {           // RMSNorm+cast: one block per row
        int row = bid - 4096;
        const float* xr = x + (size_t)row * ND;
        float4 v = ((const float4*)xr)[tid];
        float ss = v.x*v.x + v.y*v.y + v.z*v.z + v.w*v.w;
        #pragma unroll
        for (int m = 32; m >= 1; m >>= 1) ss += __shfl_xor(ss, m);
        if ((tid & 63) == 0) wsum[tid >> 6] = ss;
        __syncthreads();
        float total = wsum[0] + wsum[1] + wsum[2] + wsum[3];
        float scale = rsqrtf(total * (1.0f / ND) + 1e-6f);
        float4 wv = ((const float4*)norm_w)[tid];
        bf16x4 o;
        o[0] = (bf16)(v.x * scale * wv.x);
        o[1] = (bf16)(v.y * scale * wv.y);
        o[2] = (bf16)(v.z * scale * wv.z);
        o[3] = (bf16)(v.w * scale * wv.w);
        ((bf16x4*)(xn + (size_t)row * ND))[tid] = o;
    } else {                           // rope table: tab[s*16+j]
        int idx = (bid - 8192) * 256 + tid;
        int s = idx >> 4, j = idx & 15;
        float f0 = powf(10000.0f, -(float)j * (1.0f / 32.0f));
        float f1 = powf(10000.0f, -(float)(j + 16) * (1.0f / 32.0f));
        float sn0, c0, sn1, c1;
        sincosf((float)s * f0, &sn0, &c0);
        sincosf((float)s * f1, &sn1, &c1);
        tab[idx] = make_float4(c0, sn0, c1, sn1);
    }
}

// ---------------- QKV GEMM (R10 BK=32 structure) + bias + fused RoPE ----------------
// Launched TWICE with rx0 = 0 / 16 (half the row-blocks each) so each dispatch is
// ~25us -> everything larger surfaces in the rocprof top-5 (visibility round).
// V stored FRAGMENT-MAJOR (R8); Q/K via LDS-transpose -> coalesced 16B stores (R10).
__global__ __launch_bounds__(256) void gemm_qkv_rope(const bf16* __restrict__ A,
                                                     const bf16* __restrict__ Bm,
                                                     const float* __restrict__ bias,
                                                     const float4* __restrict__ tab,
                                                     bf16* __restrict__ Qb,
                                                     bf16* __restrict__ Kb,
                                                     bf16* __restrict__ Vf,
                                                     int rx0) {
    const int K = ND;
    __shared__ bf16 smem[8192];        // Asm[0:4096) | Bsm[4096:8192)
    bf16* Asm = smem;
    bf16* Bsm = smem + 4096;
    const int tid = threadIdx.x;
    const int wave = tid >> 6, lane = tid & 63;
    const int quad = lane >> 4, l15 = lane & 15;
    const int row0 = (blockIdx.x + rx0) * 128, col0 = blockIdx.y * 128;
    const int wr = (wave >> 1) * 64, wc = (wave & 1) * 64;
    const int srow = lane >> 2;
    const int scol = (lane & 3) * 8;

    f32x4 acc[4][4] = {};

    for (int k0 = 0; k0 < K; k0 += 32) {
        #pragma unroll
        for (int i = 0; i < 2; ++i) {
            int r = wave * 32 + i * 16;
            gll16(A + (size_t)(row0 + r + srow) * K + k0 + scol, Asm + r * 32);
            gll16(Bm + (size_t)(col0 + r + srow) * K + k0 + scol, Bsm + r * 32);
        }
        __syncthreads();
        bf16x8 af[4], bff[4];
        #pragma unroll
        for (int t = 0; t < 4; ++t) {
            af[t]  = *(const bf16x8*)(Asm + (wr + t * 16 + l15) * 32 + quad * 8);
            bff[t] = *(const bf16x8*)(Bsm + (wc + t * 16 + l15) * 32 + quad * 8);
        }
        #pragma unroll
        for (int mt = 0; mt < 4; ++mt)
            #pragma unroll
            for (int nt = 0; nt < 4; ++nt)
                acc[mt][nt] = mfma16(af[mt], bff[nt], acc[mt][nt]);
        __syncthreads();
    }

    float bb[4];
    #pragma unroll
    for (int nt = 0; nt < 4; ++nt) bb[nt] = bias[col0 + wc + nt * 16 + l15];

    const int region = col0 >> 10;   // 0=Q, 1=K, 2=V
    if (region == 2) {
        const int cv = col0 - 2048 + wc;
        const int h = cv >> 6;
        const int b = row0 >> 11;
        const int sloc = row0 & (NS - 1);
        const int kg0 = (sloc + wr) >> 5;
        bf16* vh = Vf + (size_t)(b * NH + h) * 131072;   // 64 kg * 4 nt * 512
        #pragma unroll
        for (int Gw = 0; Gw < 2; ++Gw) {
            #pragma unroll
            for (int nt = 0; nt < 4; ++nt) {
                bf16x8 vf8;
                #pragma unroll
                for (int r = 0; r < 4; ++r) {
                    vf8[r]     = (bf16)(acc[2 * Gw][nt][r] + bb[nt]);
                    vf8[4 + r] = (bf16)(acc[2 * Gw + 1][nt][r] + bb[nt]);
                }
                *(bf16x8*)(vh + ((size_t)(kg0 + Gw) * 4 + nt) * 512 + lane * 8) = vf8;
            }
        }
    } else {
        const float scale = (region == 0) ? 0.125f : 1.0f;
        bf16* Ob = (region == 0) ? Qb : Kb;
        const int h = ((col0 + wc) & 1023) >> 6;
        bf16* ep = smem + wave * 2048;         // per-wave 32x64 transpose tile
        #pragma unroll
        for (int p = 0; p < 2; ++p) {
            #pragma unroll
            for (int mtl = 0; mtl < 2; ++mtl) {
                const int mt = p * 2 + mtl;
                #pragma unroll
                for (int r = 0; r < 4; ++r) {
                    int row = row0 + wr + mt * 16 + quad * 4 + r;
                    int s = row & (NS - 1);
                    float4 cs = tab[s * 16 + l15];
                    #pragma unroll
                    for (int nt = 0; nt < 4; ++nt) {
                        float v  = acc[mt][nt][r] + bb[nt];
                        float vp = acc[mt][nt ^ 2][r] + bb[nt ^ 2];
                        float cc = (nt & 1) ? cs.z : cs.x;
                        float ss = (nt & 1) ? cs.w : cs.y;
                        float res = (nt < 2) ? (v * cc - vp * ss) : (v * cc + vp * ss);
                        ep[(mtl * 16 + quad * 4 + r) * 64 + nt * 16 + l15] = (bf16)(res * scale);
                    }
                }
            }
            asm volatile("s_waitcnt lgkmcnt(0)" ::: "memory");
            const int rowp = row0 + wr + p * 32;
            const int b = rowp >> 11;
            const int s0p = rowp & (NS - 1);
            bf16* gbase = Ob + ((size_t)(b * NH + h) * NS + s0p + (lane >> 3)) * 64 + (lane & 7) * 8;
            const bf16* lbase = ep + (lane >> 3) * 64 + (lane & 7) * 8;
            #pragma unroll
            for (int i = 0; i < 4; ++i) {
                bf16x8 v8 = *(const bf16x8*)(lbase + i * 512);
                *(bf16x8*)(gbase + (size_t)i * 512) = v8;
            }
            asm volatile("s_waitcnt lgkmcnt(0)" ::: "memory");
        }
    }
}

// ---------------- proj GEMM (R10): C[4096,1024] = A @ B^T + bias, fp32 out; 128x64 tile ----------------
__global__ __launch_bounds__(256) void gemm_proj(const bf16* __restrict__ A,
                                                 const bf16* __restrict__ Bm,
                                                 const float* __restrict__ bias,
                                                 float* __restrict__ C) {
    __shared__ bf16 Asm[128 * 32];
    __shared__ bf16 Bsm[64 * 32];
    const int tid = threadIdx.x;
    const int wave = tid >> 6, lane = tid & 63;
    const int quad = lane >> 4, l15 = lane & 15;
    const int row0 = blockIdx.x * 128, col0 = blockIdx.y * 64;
    const int wr = (wave >> 1) * 64, wc = (wave & 1) * 32;
    const int srow = lane >> 2;
    const int scol = (lane & 3) * 8;

    f32x4 acc[4][2] = {};

    for (int k0 = 0; k0 < ND; k0 += 32) {
        gll16(A + (size_t)(row0 + wave * 32 + srow) * ND + k0 + scol, Asm + (wave * 32) * 32);
        gll16(A + (size_t)(row0 + wave * 32 + 16 + srow) * ND + k0 + scol, Asm + (wave * 32 + 16) * 32);
        gll16(Bm + (size_t)(col0 + wave * 16 + srow) * ND + k0 + scol, Bsm + (wave * 16) * 32);
        __syncthreads();
        bf16x8 af[4], bff[2];
        #pragma unroll
        for (int t = 0; t < 4; ++t)
            af[t] = *(const bf16x8*)(Asm + (wr + t * 16 + l15) * 32 + quad * 8);
        #pragma unroll
        for (int t = 0; t < 2; ++t)
            bff[t] = *(const bf16x8*)(Bsm + (wc + t * 16 + l15) * 32 + quad * 8);
        #pragma unroll
        for (int mt = 0; mt < 4; ++mt)
            #pragma unroll
            for (int nt = 0; nt < 2; ++nt)
                acc[mt][nt] = mfma16(af[mt], bff[nt], acc[mt][nt]);
        __syncthreads();
    }

    #pragma unroll
    for (int nt = 0; nt < 2; ++nt) {
        int col = col0 + wc + nt * 16 + l15;
        float bv = bias[col];
        #pragma unroll
        for (int mt = 0; mt < 4; ++mt) {
            int row = row0 + wr + mt * 16 + quad * 4;
            #pragma unroll
            for (int r = 0; r < 4; ++r)
                C[(size_t)(row + r) * ND + col] = acc[mt][nt][r] + bv;
        }
    }
}

// ---------------- flash attention (R10): frag-major V, dbuf staging, coalesced Y epilogue ----------------
__global__ __launch_bounds__(256) void attn(const bf16* __restrict__ Q,
                                            const bf16* __restrict__ K,
                                            const bf16* __restrict__ Vf,
                                            bf16* __restrict__ Y) {
    __shared__ bf16 Ksm[2][8192];
    __shared__ bf16 Vsm[2][8192];
    int bid = blockIdx.x;
    int g = bid >> 5;
    int bh = bid & 31;
    int qt = (g < 8) ? (15 - g) : (g - 8);
    int tid = threadIdx.x;
    int wave = tid >> 6, lane = tid & 63;
    int quad = lane >> 4, l15 = lane & 15;
    int q0 = qt * 128 + wave * 32;
    const bf16* Qh = Q + (size_t)bh * NS * 64;
    const bf16* Kh = K + (size_t)bh * NS * 64;
    const float NEG_INF = -__builtin_inff();

    const int krow = wave * 8 + (lane >> 3);
    const int ksx  = (lane & 7) ^ (krow & 7);
    const bf16* sK = Kh + (size_t)krow * 64 + ksx * 8;
    const bf16* sV = Vf + (size_t)bh * 131072 + wave * 2048 + lane * 8;

    const bf16* pk0 = &Ksm[0][l15 * 64 + ((quad) ^ (l15 & 7)) * 8];
    const bf16* pk1 = &Ksm[0][l15 * 64 + ((4 + quad) ^ (l15 & 7)) * 8];
    const bf16* pvf = &Vsm[0][lane * 8];

    bf16x8 bq[2][2];
    #pragma unroll
    for (int t = 0; t < 2; ++t)
        #pragma unroll
        for (int hh = 0; hh < 2; ++hh)
            bq[t][hh] = *(const bf16x8*)(Qh + (size_t)(q0 + t * 16 + l15) * 64 + hh * 32 + quad * 8);

    f32x4 o[2][4] = {};
    float lsum[2] = {0.f, 0.f};

    auto stage = [&](int c, int par) {
        const int kb = c * 128;
        bf16* dK = &Ksm[par][wave * 512];
        bf16* dV = &Vsm[par][wave * 2048];
        #pragma unroll
        for (int i = 0; i < 4; ++i)
            gll16(sK + (size_t)(kb + i * 32) * 64, dK + i * 2048);
        #pragma unroll
        for (int nt = 0; nt < 4; ++nt)
            gll16(sV + (size_t)(kb >> 5) * 2048 + nt * 512, dV + nt * 512);
    };

    auto compute = [&](int cc, int par) {
        const int kb = cc * 128;
        const int pb = par * 8192;
        #pragma unroll
        for (int ksub = 0; ksub < 4; ++ksub) {
            const int kbs = kb + ksub * 32;
            if (kbs <= q0) {
                bf16x8 ak00 = *(const bf16x8*)(pk0 + pb + ksub * 2048);
                bf16x8 ak01 = *(const bf16x8*)(pk1 + pb + ksub * 2048);
                bf16x8 ak10 = *(const bf16x8*)(pk0 + pb + ksub * 2048 + 1024);
                bf16x8 ak11 = *(const bf16x8*)(pk1 + pb + ksub * 2048 + 1024);
                bf16x8 vf0 = *(const bf16x8*)(pvf + pb + ksub * 2048);
                bf16x8 vf1 = *(const bf16x8*)(pvf + pb + ksub * 2048 + 512);
                bf16x8 vf2 = *(const bf16x8*)(pvf + pb + ksub * 2048 + 1024);
                bf16x8 vf3 = *(const bf16x8*)(pvf + pb + ksub * 2048 + 1536);
                const bool masked = (kbs == q0);
                #pragma unroll
                for (int t = 0; t < 2; ++t) {
                    f32x4 sh0 = {}, sh1 = {};
                    sh0 = mfma16(ak00, bq[t][0], sh0);
                    sh0 = mfma16(ak01, bq[t][1], sh0);
                    sh1 = mfma16(ak10, bq[t][0], sh1);
                    sh1 = mfma16(ak11, bq[t][1], sh1);
                    if (masked) {
                        int qy = q0 + t * 16 + l15;
                        #pragma unroll
                        for (int r = 0; r < 4; ++r) {
                            if (kbs + quad * 4 + r > qy)      sh0[r] = NEG_INF;
                            if (kbs + 16 + quad * 4 + r > qy) sh1[r] = NEG_INF;
                        }
                    }
                    bf16x8 pa;
                    float ls = 0.f;
                    #pragma unroll
                    for (int j = 0; j < 4; ++j) {
                        float p0 = __expf(sh0[j]);
                        float p1 = __expf(sh1[j]);
                        ls += p0 + p1;
                        pa[j] = (bf16)p0;
                        pa[4 + j] = (bf16)p1;
                    }
                    lsum[t] += ls;
                    o[t][0] = mfma16(pa, vf0, o[t][0]);
                    o[t][1] = mfma16(pa, vf1, o[t][1]);
                    o[t][2] = mfma16(pa, vf2, o[t][2]);
                    o[t][3] = mfma16(pa, vf3, o[t][3]);
                }
            }
        }
    };

    const int ncb = qt + 1;
    stage(0, 0);
    __syncthreads();
    for (int c = 0; c < ncb; ++c) {
        const int par = c & 1;
        if (c + 1 < ncb) stage(c + 1, par ^ 1);
        compute(c, par);
        __syncthreads();
    }

    int b = bh >> 4, h = bh & 15;
    bf16* ep = &Ksm[0][wave * 2048];
    #pragma unroll
    for (int t = 0; t < 2; ++t) {
        float red = lsum[t];
        red += __shfl_xor(red, 16);
        red += __shfl_xor(red, 32);
        #pragma unroll
        for (int r = 0; r < 4; ++r) {
            float il = 1.0f / __shfl(red, quad * 4 + r);
            #pragma unroll
            for (int nt = 0; nt < 4; ++nt)
                ep[(t * 16 + quad * 4 + r) * 64 + nt * 16 + l15] = (bf16)(o[t][nt][r] * il);
        }
    }
    asm volatile("s_waitcnt lgkmcnt(0)" ::: "memory");
    bf16* gbase = Y + ((size_t)(b * NS + q0 + (lane >> 3)) << 10) + h * 64 + (lane & 7) * 8;
    const bf16* lbase = ep + (lane >> 3) * 64 + (lane & 7) * 8;
    #pragma unroll
    for (int i = 0; i < 4; ++i) {
        bf16x8 v8 = *(const bf16x8*)(lbase + i * 512);
        *(bf16x8*)(gbase + ((size_t)i * 8 << 10)) = v8;
    }
}

// ---------------- host launch ----------------
extern "C" void kernel_launch(void* const* d_in, const int* in_sizes, int n_in,
                              void* d_out, int out_size, void* d_ws, size_t ws_size,
                              hipStream_t stream) {
    const float* x      = (const float*)d_in[0];
    const float* norm_w = (const float*)d_in[1];
    const float* qkv_w  = (const float*)d_in[2];
    const float* qkv_b  = (const float*)d_in[3];
    const float* proj_w = (const float*)d_in[4];
    const float* proj_b = (const float*)d_in[5];
    float* out = (float*)d_out;

    char* ws = (char*)d_ws;
    size_t off = 0;
    bf16* xn    = (bf16*)(ws + off); off += (size_t)ROWS * ND * 2;
    bf16* wq    = (bf16*)(ws + off); off += (size_t)E3 * ND * 2;
    bf16* wp    = (bf16*)(ws + off); off += (size_t)ND * ND * 2;   // contiguous after wq
    bf16* Qb    = (bf16*)(ws + off); off += (size_t)NB * NH * NS * HD * 2;
    bf16* Kb    = (bf16*)(ws + off); off += (size_t)NB * NH * NS * HD * 2;
    bf16* Vfrag = (bf16*)(ws + off); off += (size_t)NB * NH * HD * NS * 2;
    bf16* Y     = (bf16*)(ws + off); off += (size_t)ROWS * ND * 2;
    float4* tab = (float4*)(ws + off); off += (size_t)NS * 16 * sizeof(float4);

    prep<<<8320, 256, 0, stream>>>(qkv_w, proj_w, x, norm_w, wq, xn, tab);
    // Two half-row launches (visibility: each ~25us so attn/proj/prep surface in top-5)
    gemm_qkv_rope<<<dim3(16, E3 / 128), 256, 0, stream>>>(xn, wq, qkv_b, tab, Qb, Kb, Vfrag, 0);
    gemm_qkv_rope<<<dim3(16, E3 / 128), 256, 0, stream>>>(xn, wq, qkv_b, tab, Qb, Kb, Vfrag, 16);
    attn<<<NB * NH * (NS / 128), 256, 0, stream>>>(Qb, Kb, Vfrag, Y);
    gemm_proj<<<dim3(ROWS / 128, ND / 64), 256, 0, stream>>>(Y, wp, proj_b, out);
}

// Round 13
// 185.794 us; speedup vs baseline: 1.0551x; 1.0511x over previous
//
#include <hip/hip_runtime.h>
#include <cstdint>
#include <cstddef>

// Problem constants: b=2, s=2048, d_model=1024, heads=16, head_dim=64
#define NB 2
#define NS 2048
#define ND 1024
#define NH 16
#define HD 64
#define ROWS 4096      // NB*NS
#define E3 3072        // 3*ND

using bf16 = __bf16;
typedef __attribute__((ext_vector_type(4))) __bf16 bf16x4;
typedef __attribute__((ext_vector_type(8))) __bf16 bf16x8;
typedef __attribute__((ext_vector_type(4))) float f32x4;

__device__ __forceinline__ f32x4 mfma16(bf16x8 a, bf16x8 b, f32x4 c) {
    return __builtin_amdgcn_mfma_f32_16x16x32_bf16(a, b, c, 0, 0, 0);
}

__device__ __forceinline__ void gll16(const bf16* src, bf16* lds) {
    __builtin_amdgcn_global_load_lds(
        (const __attribute__((address_space(1))) void*)src,
        (__attribute__((address_space(3))) void*)lds, 16, 0, 0);
}

// ---------------- fused prep: weight cast | rmsnorm | rope table (independent) ----------------
__global__ __launch_bounds__(256) void prep(const float* __restrict__ qkv_w,
                                            const float* __restrict__ proj_w,
                                            const float* __restrict__ x,
                                            const float* __restrict__ norm_w,
                                            bf16* __restrict__ wq,
                                            bf16* __restrict__ xn,
                                            float4* __restrict__ tab) {
    __shared__ float wsum[4];
    int bid = blockIdx.x;
    int tid = threadIdx.x;
    if (bid < 4096) {                  // weight cast: 4M elems, 4/thread
        const int n1 = E3 * ND;
        int i = (bid * 256 + tid) * 4;
        const float* src = (i < n1) ? (qkv_w + i) : (proj_w + (i - n1));
        float4 v = *(const float4*)src;
        bf16x4 o;
        o[0] = (bf16)v.x; o[1] = (bf16)v.y; o[2] = (bf16)v.z; o[3] = (bf16)v.w;
        *(bf16x4*)(wq + i) = o;
    } else if (bid < 8192) {           // RMSNorm+cast: one block per row
        int row = bid - 4096;
        const float* xr = x + (size_t)row * ND;
        float4 v = ((const float4*)xr)[tid];
        float ss = v.x*v.x + v.y*v.y + v.z*v.z + v.w*v.w;
        #pragma unroll
        for (int m = 32; m >= 1; m >>= 1) ss += __shfl_xor(ss, m);
        if ((tid & 63) == 0) wsum[tid >> 6] = ss;
        __syncthreads();
        float total = wsum[0] + wsum[1] + wsum[2] + wsum[3];
        float scale = rsqrtf(total * (1.0f / ND) + 1e-6f);
        float4 wv = ((const float4*)norm_w)[tid];
        bf16x4 o;
        o[0] = (bf16)(v.x * scale * wv.x);
        o[1] = (bf16)(v.y * scale * wv.y);
        o[2] = (bf16)(v.z * scale * wv.z);
        o[3] = (bf16)(v.w * scale * wv.w);
        ((bf16x4*)(xn + (size_t)row * ND))[tid] = o;
    } else {                           // rope table: tab[s*16+j]
        int idx = (bid - 8192) * 256 + tid;
        int s = idx >> 4, j = idx & 15;
        float f0 = powf(10000.0f, -(float)j * (1.0f / 32.0f));
        float f1 = powf(10000.0f, -(float)(j + 16) * (1.0f / 32.0f));
        float sn0, c0, sn1, c1;
        sincosf((float)s * f0, &sn0, &c0);
        sincosf((float)s * f1, &sn1, &c1);
        tab[idx] = make_float4(c0, sn0, c1, sn1);
    }
}

// ---------------- QKV GEMM (R10) + bias + fused RoPE; single launch ----------------
__global__ __launch_bounds__(256) void gemm_qkv_rope(const bf16* __restrict__ A,
                                                     const bf16* __restrict__ Bm,
                                                     const float* __restrict__ bias,
                                                     const float4* __restrict__ tab,
                                                     bf16* __restrict__ Qb,
                                                     bf16* __restrict__ Kb,
                                                     bf16* __restrict__ Vf) {
    const int K = ND;
    __shared__ bf16 smem[8192];        // Asm[0:4096) | Bsm[4096:8192)
    bf16* Asm = smem;
    bf16* Bsm = smem + 4096;
    const int tid = threadIdx.x;
    const int wave = tid >> 6, lane = tid & 63;
    const int quad = lane >> 4, l15 = lane & 15;
    const int row0 = blockIdx.x * 128, col0 = blockIdx.y * 128;
    const int wr = (wave >> 1) * 64, wc = (wave & 1) * 64;
    const int srow = lane >> 2;
    const int scol = (lane & 3) * 8;

    f32x4 acc[4][4] = {};

    for (int k0 = 0; k0 < K; k0 += 32) {
        #pragma unroll
        for (int i = 0; i < 2; ++i) {
            int r = wave * 32 + i * 16;
            gll16(A + (size_t)(row0 + r + srow) * K + k0 + scol, Asm + r * 32);
            gll16(Bm + (size_t)(col0 + r + srow) * K + k0 + scol, Bsm + r * 32);
        }
        __syncthreads();
        bf16x8 af[4], bff[4];
        #pragma unroll
        for (int t = 0; t < 4; ++t) {
            af[t]  = *(const bf16x8*)(Asm + (wr + t * 16 + l15) * 32 + quad * 8);
            bff[t] = *(const bf16x8*)(Bsm + (wc + t * 16 + l15) * 32 + quad * 8);
        }
        #pragma unroll
        for (int mt = 0; mt < 4; ++mt)
            #pragma unroll
            for (int nt = 0; nt < 4; ++nt)
                acc[mt][nt] = mfma16(af[mt], bff[nt], acc[mt][nt]);
        __syncthreads();
    }

    float bb[4];
    #pragma unroll
    for (int nt = 0; nt < 4; ++nt) bb[nt] = bias[col0 + wc + nt * 16 + l15];

    const int region = col0 >> 10;   // 0=Q, 1=K, 2=V
    if (region == 2) {
        const int cv = col0 - 2048 + wc;
        const int h = cv >> 6;
        const int b = row0 >> 11;
        const int sloc = row0 & (NS - 1);
        const int kg0 = (sloc + wr) >> 5;
        bf16* vh = Vf + (size_t)(b * NH + h) * 131072;   // 64 kg * 4 nt * 512
        #pragma unroll
        for (int Gw = 0; Gw < 2; ++Gw) {
            #pragma unroll
            for (int nt = 0; nt < 4; ++nt) {
                bf16x8 vf8;
                #pragma unroll
                for (int r = 0; r < 4; ++r) {
                    vf8[r]     = (bf16)(acc[2 * Gw][nt][r] + bb[nt]);
                    vf8[4 + r] = (bf16)(acc[2 * Gw + 1][nt][r] + bb[nt]);
                }
                *(bf16x8*)(vh + ((size_t)(kg0 + Gw) * 4 + nt) * 512 + lane * 8) = vf8;
            }
        }
    } else {
        const float scale = (region == 0) ? 0.125f : 1.0f;
        bf16* Ob = (region == 0) ? Qb : Kb;
        const int h = ((col0 + wc) & 1023) >> 6;
        bf16* ep = smem + wave * 2048;         // per-wave 32x64 transpose tile
        #pragma unroll
        for (int p = 0; p < 2; ++p) {
            #pragma unroll
            for (int mtl = 0; mtl < 2; ++mtl) {
                const int mt = p * 2 + mtl;
                #pragma unroll
                for (int r = 0; r < 4; ++r) {
                    int row = row0 + wr + mt * 16 + quad * 4 + r;
                    int s = row & (NS - 1);
                    float4 cs = tab[s * 16 + l15];
                    #pragma unroll
                    for (int nt = 0; nt < 4; ++nt) {
                        float v  = acc[mt][nt][r] + bb[nt];
                        float vp = acc[mt][nt ^ 2][r] + bb[nt ^ 2];
                        float cc = (nt & 1) ? cs.z : cs.x;
                        float ss = (nt & 1) ? cs.w : cs.y;
                        float res = (nt < 2) ? (v * cc - vp * ss) : (v * cc + vp * ss);
                        ep[(mtl * 16 + quad * 4 + r) * 64 + nt * 16 + l15] = (bf16)(res * scale);
                    }
                }
            }
            asm volatile("s_waitcnt lgkmcnt(0)" ::: "memory");
            const int rowp = row0 + wr + p * 32;
            const int b = rowp >> 11;
            const int s0p = rowp & (NS - 1);
            bf16* gbase = Ob + ((size_t)(b * NH + h) * NS + s0p + (lane >> 3)) * 64 + (lane & 7) * 8;
            const bf16* lbase = ep + (lane >> 3) * 64 + (lane & 7) * 8;
            #pragma unroll
            for (int i = 0; i < 4; ++i) {
                bf16x8 v8 = *(const bf16x8*)(lbase + i * 512);
                *(bf16x8*)(gbase + (size_t)i * 512) = v8;
            }
            asm volatile("s_waitcnt lgkmcnt(0)" ::: "memory");
        }
    }
}

// ---------------- proj GEMM (R10): C[4096,1024] = A @ B^T + bias, fp32 out; 128x64 tile ----------------
__global__ __launch_bounds__(256) void gemm_proj(const bf16* __restrict__ A,
                                                 const bf16* __restrict__ Bm,
                                                 const float* __restrict__ bias,
                                                 float* __restrict__ C) {
    __shared__ bf16 Asm[128 * 32];
    __shared__ bf16 Bsm[64 * 32];
    const int tid = threadIdx.x;
    const int wave = tid >> 6, lane = tid & 63;
    const int quad = lane >> 4, l15 = lane & 15;
    const int row0 = blockIdx.x * 128, col0 = blockIdx.y * 64;
    const int wr = (wave >> 1) * 64, wc = (wave & 1) * 32;
    const int srow = lane >> 2;
    const int scol = (lane & 3) * 8;

    f32x4 acc[4][2] = {};

    for (int k0 = 0; k0 < ND; k0 += 32) {
        gll16(A + (size_t)(row0 + wave * 32 + srow) * ND + k0 + scol, Asm + (wave * 32) * 32);
        gll16(A + (size_t)(row0 + wave * 32 + 16 + srow) * ND + k0 + scol, Asm + (wave * 32 + 16) * 32);
        gll16(Bm + (size_t)(col0 + wave * 16 + srow) * ND + k0 + scol, Bsm + (wave * 16) * 32);
        __syncthreads();
        bf16x8 af[4], bff[2];
        #pragma unroll
        for (int t = 0; t < 4; ++t)
            af[t] = *(const bf16x8*)(Asm + (wr + t * 16 + l15) * 32 + quad * 8);
        #pragma unroll
        for (int t = 0; t < 2; ++t)
            bff[t] = *(const bf16x8*)(Bsm + (wc + t * 16 + l15) * 32 + quad * 8);
        #pragma unroll
        for (int mt = 0; mt < 4; ++mt)
            #pragma unroll
            for (int nt = 0; nt < 2; ++nt)
                acc[mt][nt] = mfma16(af[mt], bff[nt], acc[mt][nt]);
        __syncthreads();
    }

    #pragma unroll
    for (int nt = 0; nt < 2; ++nt) {
        int col = col0 + wc + nt * 16 + l15;
        float bv = bias[col];
        #pragma unroll
        for (int mt = 0; mt < 4; ++mt) {
            int row = row0 + wr + mt * 16 + quad * 4;
            #pragma unroll
            for (int r = 0; r < 4; ++r)
                C[(size_t)(row + r) * ND + col] = acc[mt][nt][r] + bv;
        }
    }
}

// ---------------- flash attention v10: forced 2-waves/EU reg budget + hoisted frag reads ----------------
// R12 counters: VGPR=88 forced each 32-key ksub into a serial ds_read->QK->exp->PV chain
// (~6k cyc/chunk vs ~2.2k issue work). LDS (64KB) caps occupancy at 2 waves/SIMD anyway,
// so amdgpu_waves_per_eu(2,2) raises the VGPR cap to ~256 for free; all 32 chunk frags
// (128 VGPRs) are hoisted into registers so the 4 ksubs' compute chains pipeline.
__global__ __launch_bounds__(256) __attribute__((amdgpu_waves_per_eu(2, 2)))
void attn(const bf16* __restrict__ Q,
          const bf16* __restrict__ K,
          const bf16* __restrict__ Vf,
          bf16* __restrict__ Y) {
    __shared__ bf16 Ksm[2][8192];
    __shared__ bf16 Vsm[2][8192];
    int bid = blockIdx.x;
    int g = bid >> 5;
    int bh = bid & 31;
    int qt = (g < 8) ? (15 - g) : (g - 8);
    int tid = threadIdx.x;
    int wave = tid >> 6, lane = tid & 63;
    int quad = lane >> 4, l15 = lane & 15;
    int q0 = qt * 128 + wave * 32;
    const bf16* Qh = Q + (size_t)bh * NS * 64;
    const bf16* Kh = K + (size_t)bh * NS * 64;
    const float NEG_INF = -__builtin_inff();

    const int krow = wave * 8 + (lane >> 3);
    const int ksx  = (lane & 7) ^ (krow & 7);
    const bf16* sK = Kh + (size_t)krow * 64 + ksx * 8;
    const bf16* sV = Vf + (size_t)bh * 131072 + wave * 2048 + lane * 8;

    const bf16* pk0 = &Ksm[0][l15 * 64 + ((quad) ^ (l15 & 7)) * 8];
    const bf16* pk1 = &Ksm[0][l15 * 64 + ((4 + quad) ^ (l15 & 7)) * 8];
    const bf16* pvf = &Vsm[0][lane * 8];

    bf16x8 bq[2][2];
    #pragma unroll
    for (int t = 0; t < 2; ++t)
        #pragma unroll
        for (int hh = 0; hh < 2; ++hh)
            bq[t][hh] = *(const bf16x8*)(Qh + (size_t)(q0 + t * 16 + l15) * 64 + hh * 32 + quad * 8);

    f32x4 o[2][4] = {};
    float lsum[2] = {0.f, 0.f};

    auto stage = [&](int c, int par) {
        const int kb = c * 128;
        bf16* dK = &Ksm[par][wave * 512];
        bf16* dV = &Vsm[par][wave * 2048];
        #pragma unroll
        for (int i = 0; i < 4; ++i)
            gll16(sK + (size_t)(kb + i * 32) * 64, dK + i * 2048);
        #pragma unroll
        for (int nt = 0; nt < 4; ++nt)
            gll16(sV + (size_t)(kb >> 5) * 2048 + nt * 512, dV + nt * 512);
    };

    auto compute = [&](int cc, int par) {
        const int kb = cc * 128;
        const int pb = par * 8192;
        // Hoist ALL frag reads for the chunk: 32 ds_read_b128 issue back-to-back,
        // then the 4 ksubs' QK->exp->PV chains overlap (needs the raised VGPR cap).
        bf16x8 ak[4][4], vf[4][4];
        #pragma unroll
        for (int ksub = 0; ksub < 4; ++ksub) {
            ak[ksub][0] = *(const bf16x8*)(pk0 + pb + ksub * 2048);
            ak[ksub][1] = *(const bf16x8*)(pk1 + pb + ksub * 2048);
            ak[ksub][2] = *(const bf16x8*)(pk0 + pb + ksub * 2048 + 1024);
            ak[ksub][3] = *(const bf16x8*)(pk1 + pb + ksub * 2048 + 1024);
            vf[ksub][0] = *(const bf16x8*)(pvf + pb + ksub * 2048);
            vf[ksub][1] = *(const bf16x8*)(pvf + pb + ksub * 2048 + 512);
            vf[ksub][2] = *(const bf16x8*)(pvf + pb + ksub * 2048 + 1024);
            vf[ksub][3] = *(const bf16x8*)(pvf + pb + ksub * 2048 + 1536);
        }
        #pragma unroll
        for (int ksub = 0; ksub < 4; ++ksub) {
            const int kbs = kb + ksub * 32;
            if (kbs <= q0) {
                const bool masked = (kbs == q0);
                #pragma unroll
                for (int t = 0; t < 2; ++t) {
                    f32x4 sh0 = {}, sh1 = {};
                    sh0 = mfma16(ak[ksub][0], bq[t][0], sh0);
                    sh0 = mfma16(ak[ksub][1], bq[t][1], sh0);
                    sh1 = mfma16(ak[ksub][2], bq[t][0], sh1);
                    sh1 = mfma16(ak[ksub][3], bq[t][1], sh1);
                    if (masked) {
                        int qy = q0 + t * 16 + l15;
                        #pragma unroll
                        for (int r = 0; r < 4; ++r) {
                            if (kbs + quad * 4 + r > qy)      sh0[r] = NEG_INF;
                            if (kbs + 16 + quad * 4 + r > qy) sh1[r] = NEG_INF;
                        }
                    }
                    bf16x8 pa;
                    float ls = 0.f;
                    #pragma unroll
                    for (int j = 0; j < 4; ++j) {
                        float p0 = __expf(sh0[j]);
                        float p1 = __expf(sh1[j]);
                        ls += p0 + p1;
                        pa[j] = (bf16)p0;
                        pa[4 + j] = (bf16)p1;
                    }
                    lsum[t] += ls;
                    o[t][0] = mfma16(pa, vf[ksub][0], o[t][0]);
                    o[t][1] = mfma16(pa, vf[ksub][1], o[t][1]);
                    o[t][2] = mfma16(pa, vf[ksub][2], o[t][2]);
                    o[t][3] = mfma16(pa, vf[ksub][3], o[t][3]);
                }
            }
        }
    };

    const int ncb = qt + 1;
    stage(0, 0);
    __syncthreads();
    for (int c = 0; c < ncb; ++c) {
        const int par = c & 1;
        if (c + 1 < ncb) stage(c + 1, par ^ 1);
        compute(c, par);
        __syncthreads();
    }

    int b = bh >> 4, h = bh & 15;
    bf16* ep = &Ksm[0][wave * 2048];
    #pragma unroll
    for (int t = 0; t < 2; ++t) {
        float red = lsum[t];
        red += __shfl_xor(red, 16);
        red += __shfl_xor(red, 32);
        #pragma unroll
        for (int r = 0; r < 4; ++r) {
            float il = 1.0f / __shfl(red, quad * 4 + r);
            #pragma unroll
            for (int nt = 0; nt < 4; ++nt)
                ep[(t * 16 + quad * 4 + r) * 64 + nt * 16 + l15] = (bf16)(o[t][nt][r] * il);
        }
    }
    asm volatile("s_waitcnt lgkmcnt(0)" ::: "memory");
    bf16* gbase = Y + ((size_t)(b * NS + q0 + (lane >> 3)) << 10) + h * 64 + (lane & 7) * 8;
    const bf16* lbase = ep + (lane >> 3) * 64 + (lane & 7) * 8;
    #pragma unroll
    for (int i = 0; i < 4; ++i) {
        bf16x8 v8 = *(const bf16x8*)(lbase + i * 512);
        *(bf16x8*)(gbase + ((size_t)i * 8 << 10)) = v8;
    }
}

// ---------------- host launch ----------------
extern "C" void kernel_launch(void* const* d_in, const int* in_sizes, int n_in,
                              void* d_out, int out_size, void* d_ws, size_t ws_size,
                              hipStream_t stream) {
    const float* x      = (const float*)d_in[0];
    const float* norm_w = (const float*)d_in[1];
    const float* qkv_w  = (const float*)d_in[2];
    const float* qkv_b  = (const float*)d_in[3];
    const float* proj_w = (const float*)d_in[4];
    const float* proj_b = (const float*)d_in[5];
    float* out = (float*)d_out;

    char* ws = (char*)d_ws;
    size_t off = 0;
    bf16* xn    = (bf16*)(ws + off); off += (size_t)ROWS * ND * 2;
    bf16* wq    = (bf16*)(ws + off); off += (size_t)E3 * ND * 2;
    bf16* wp    = (bf16*)(ws + off); off += (size_t)ND * ND * 2;   // contiguous after wq
    bf16* Qb    = (bf16*)(ws + off); off += (size_t)NB * NH * NS * HD * 2;
    bf16* Kb    = (bf16*)(ws + off); off += (size_t)NB * NH * NS * HD * 2;
    bf16* Vfrag = (bf16*)(ws + off); off += (size_t)NB * NH * HD * NS * 2;
    bf16* Y     = (bf16*)(ws + off); off += (size_t)ROWS * ND * 2;
    float4* tab = (float4*)(ws + off); off += (size_t)NS * 16 * sizeof(float4);

    prep<<<8320, 256, 0, stream>>>(qkv_w, proj_w, x, norm_w, wq, xn, tab);
    gemm_qkv_rope<<<dim3(ROWS / 128, E3 / 128), 256, 0, stream>>>(xn, wq, qkv_b, tab, Qb, Kb, Vfrag);
    attn<<<NB * NH * (NS / 128), 256, 0, stream>>>(Qb, Kb, Vfrag, Y);
    gemm_proj<<<dim3(ROWS / 128, ND / 64), 256, 0, stream>>>(Y, wp, proj_b, out);
}

// Round 14
// 172.835 us; speedup vs baseline: 1.1342x; 1.0750x over previous
//
#include <hip/hip_runtime.h>
#include <cstdint>
#include <cstddef>

// Problem constants: b=2, s=2048, d_model=1024, heads=16, head_dim=64
#define NB 2
#define NS 2048
#define ND 1024
#define NH 16
#define HD 64
#define ROWS 4096      // NB*NS
#define E3 3072        // 3*ND

using bf16 = __bf16;
typedef __attribute__((ext_vector_type(4))) __bf16 bf16x4;
typedef __attribute__((ext_vector_type(8))) __bf16 bf16x8;
typedef __attribute__((ext_vector_type(4))) float f32x4;

__device__ __forceinline__ f32x4 mfma16(bf16x8 a, bf16x8 b, f32x4 c) {
    return __builtin_amdgcn_mfma_f32_16x16x32_bf16(a, b, c, 0, 0, 0);
}

__device__ __forceinline__ void gll16(const bf16* src, bf16* lds) {
    __builtin_amdgcn_global_load_lds(
        (const __attribute__((address_space(1))) void*)src,
        (__attribute__((address_space(3))) void*)lds, 16, 0, 0);
}

// ---------------- fused prep: weight cast | rmsnorm | rope table (independent) ----------------
__global__ __launch_bounds__(256) void prep(const float* __restrict__ qkv_w,
                                            const float* __restrict__ proj_w,
                                            const float* __restrict__ x,
                                            const float* __restrict__ norm_w,
                                            bf16* __restrict__ wq,
                                            bf16* __restrict__ xn,
                                            float4* __restrict__ tab) {
    __shared__ float wsum[4];
    int bid = blockIdx.x;
    int tid = threadIdx.x;
    if (bid < 4096) {                  // weight cast: 4M elems, 4/thread
        const int n1 = E3 * ND;
        int i = (bid * 256 + tid) * 4;
        const float* src = (i < n1) ? (qkv_w + i) : (proj_w + (i - n1));
        float4 v = *(const float4*)src;
        bf16x4 o;
        o[0] = (bf16)v.x; o[1] = (bf16)v.y; o[2] = (bf16)v.z; o[3] = (bf16)v.w;
        *(bf16x4*)(wq + i) = o;
    } else if (bid < 8192) {           // RMSNorm+cast: one block per row
        int row = bid - 4096;
        const float* xr = x + (size_t)row * ND;
        float4 v = ((const float4*)xr)[tid];
        float ss = v.x*v.x + v.y*v.y + v.z*v.z + v.w*v.w;
        #pragma unroll
        for (int m = 32; m >= 1; m >>= 1) ss += __shfl_xor(ss, m);
        if ((tid & 63) == 0) wsum[tid >> 6] = ss;
        __syncthreads();
        float total = wsum[0] + wsum[1] + wsum[2] + wsum[3];
        float scale = rsqrtf(total * (1.0f / ND) + 1e-6f);
        float4 wv = ((const float4*)norm_w)[tid];
        bf16x4 o;
        o[0] = (bf16)(v.x * scale * wv.x);
        o[1] = (bf16)(v.y * scale * wv.y);
        o[2] = (bf16)(v.z * scale * wv.z);
        o[3] = (bf16)(v.w * scale * wv.w);
        ((bf16x4*)(xn + (size_t)row * ND))[tid] = o;
    } else {                           // rope table: tab[s*16+j]
        int idx = (bid - 8192) * 256 + tid;
        int s = idx >> 4, j = idx & 15;
        float f0 = powf(10000.0f, -(float)j * (1.0f / 32.0f));
        float f1 = powf(10000.0f, -(float)(j + 16) * (1.0f / 32.0f));
        float sn0, c0, sn1, c1;
        sincosf((float)s * f0, &sn0, &c0);
        sincosf((float)s * f1, &sn1, &c1);
        tab[idx] = make_float4(c0, sn0, c1, sn1);
    }
}

// ---------------- QKV GEMM + RoPE: BK=32 with LDS DOUBLE-BUFFER (1 barrier/iter) ----------------
// R11 lesson: BK=64 kept the drain cost (bytes/barrier doubled) and paid occupancy.
// Dbuf at BK=32 keeps LDS at 32KB (>=3 blocks/CU) and VGPRs unchanged, halves barriers,
// AND the vmcnt(0) drain at each barrier now waits on loads issued a full compute-phase
// earlier (covered), instead of loads issued immediately before the barrier (exposed).
__global__ __launch_bounds__(256) void gemm_qkv_rope(const bf16* __restrict__ A,
                                                     const bf16* __restrict__ Bm,
                                                     const float* __restrict__ bias,
                                                     const float4* __restrict__ tab,
                                                     bf16* __restrict__ Qb,
                                                     bf16* __restrict__ Kb,
                                                     bf16* __restrict__ Vf) {
    const int K = ND;
    __shared__ bf16 smem[16384];       // A0[0:4096) A1[4096:8192) B0[8192:12288) B1[12288:16384)
    const int tid = threadIdx.x;
    const int wave = tid >> 6, lane = tid & 63;
    const int quad = lane >> 4, l15 = lane & 15;
    const int row0 = blockIdx.x * 128, col0 = blockIdx.y * 128;
    const int wr = (wave >> 1) * 64, wc = (wave & 1) * 64;
    const int srow = lane >> 2;
    const int scol = (lane & 3) * 8;

    f32x4 acc[4][4] = {};

    auto stage = [&](int k0, int p) {
        bf16* Ad = smem + p * 4096;
        bf16* Bd = smem + 8192 + p * 4096;
        #pragma unroll
        for (int i = 0; i < 2; ++i) {
            int r = wave * 32 + i * 16;
            gll16(A + (size_t)(row0 + r + srow) * K + k0 + scol, Ad + r * 32);
            gll16(Bm + (size_t)(col0 + r + srow) * K + k0 + scol, Bd + r * 32);
        }
    };

    stage(0, 0);
    __syncthreads();
    for (int k0 = 0; k0 < K; k0 += 32) {
        const int p = (k0 >> 5) & 1;
        if (k0 + 32 < K) stage(k0 + 32, p ^ 1);
        const bf16* As = smem + p * 4096;
        const bf16* Bs = smem + 8192 + p * 4096;
        bf16x8 af[4], bff[4];
        #pragma unroll
        for (int t = 0; t < 4; ++t) {
            af[t]  = *(const bf16x8*)(As + (wr + t * 16 + l15) * 32 + quad * 8);
            bff[t] = *(const bf16x8*)(Bs + (wc + t * 16 + l15) * 32 + quad * 8);
        }
        #pragma unroll
        for (int mt = 0; mt < 4; ++mt)
            #pragma unroll
            for (int nt = 0; nt < 4; ++nt)
                acc[mt][nt] = mfma16(af[mt], bff[nt], acc[mt][nt]);
        __syncthreads();   // waves done reading buf p (overwritten next iter); drains prefetch (covered)
    }

    float bb[4];
    #pragma unroll
    for (int nt = 0; nt < 4; ++nt) bb[nt] = bias[col0 + wc + nt * 16 + l15];

    const int region = col0 >> 10;   // 0=Q, 1=K, 2=V
    if (region == 2) {
        const int cv = col0 - 2048 + wc;
        const int h = cv >> 6;
        const int b = row0 >> 11;
        const int sloc = row0 & (NS - 1);
        const int kg0 = (sloc + wr) >> 5;
        bf16* vh = Vf + (size_t)(b * NH + h) * 131072;   // 64 kg * 4 nt * 512
        #pragma unroll
        for (int Gw = 0; Gw < 2; ++Gw) {
            #pragma unroll
            for (int nt = 0; nt < 4; ++nt) {
                bf16x8 vf8;
                #pragma unroll
                for (int r = 0; r < 4; ++r) {
                    vf8[r]     = (bf16)(acc[2 * Gw][nt][r] + bb[nt]);
                    vf8[4 + r] = (bf16)(acc[2 * Gw + 1][nt][r] + bb[nt]);
                }
                *(bf16x8*)(vh + ((size_t)(kg0 + Gw) * 4 + nt) * 512 + lane * 8) = vf8;
            }
        }
    } else {
        const float scale = (region == 0) ? 0.125f : 1.0f;
        bf16* Ob = (region == 0) ? Qb : Kb;
        const int h = ((col0 + wc) & 1023) >> 6;
        bf16* ep = smem + wave * 2048;         // per-wave 32x64 transpose tile (smem now dead)
        #pragma unroll
        for (int p = 0; p < 2; ++p) {
            #pragma unroll
            for (int mtl = 0; mtl < 2; ++mtl) {
                const int mt = p * 2 + mtl;
                #pragma unroll
                for (int r = 0; r < 4; ++r) {
                    int row = row0 + wr + mt * 16 + quad * 4 + r;
                    int s = row & (NS - 1);
                    float4 cs = tab[s * 16 + l15];
                    #pragma unroll
                    for (int nt = 0; nt < 4; ++nt) {
                        float v  = acc[mt][nt][r] + bb[nt];
                        float vp = acc[mt][nt ^ 2][r] + bb[nt ^ 2];
                        float cc = (nt & 1) ? cs.z : cs.x;
                        float ss = (nt & 1) ? cs.w : cs.y;
                        float res = (nt < 2) ? (v * cc - vp * ss) : (v * cc + vp * ss);
                        ep[(mtl * 16 + quad * 4 + r) * 64 + nt * 16 + l15] = (bf16)(res * scale);
                    }
                }
            }
            asm volatile("s_waitcnt lgkmcnt(0)" ::: "memory");
            const int rowp = row0 + wr + p * 32;
            const int b = rowp >> 11;
            const int s0p = rowp & (NS - 1);
            bf16* gbase = Ob + ((size_t)(b * NH + h) * NS + s0p + (lane >> 3)) * 64 + (lane & 7) * 8;
            const bf16* lbase = ep + (lane >> 3) * 64 + (lane & 7) * 8;
            #pragma unroll
            for (int i = 0; i < 4; ++i) {
                bf16x8 v8 = *(const bf16x8*)(lbase + i * 512);
                *(bf16x8*)(gbase + (size_t)i * 512) = v8;
            }
            asm volatile("s_waitcnt lgkmcnt(0)" ::: "memory");
        }
    }
}

// ---------------- proj GEMM: 128x64 tile, BK=32, LDS double-buffer ----------------
__global__ __launch_bounds__(256) void gemm_proj(const bf16* __restrict__ A,
                                                 const bf16* __restrict__ Bm,
                                                 const float* __restrict__ bias,
                                                 float* __restrict__ C) {
    __shared__ bf16 smem[12288];       // A0[0:4096) A1[4096:8192) B0[8192:10240) B1[10240:12288)
    const int tid = threadIdx.x;
    const int wave = tid >> 6, lane = tid & 63;
    const int quad = lane >> 4, l15 = lane & 15;
    const int row0 = blockIdx.x * 128, col0 = blockIdx.y * 64;
    const int wr = (wave >> 1) * 64, wc = (wave & 1) * 32;
    const int srow = lane >> 2;
    const int scol = (lane & 3) * 8;

    f32x4 acc[4][2] = {};

    auto stage = [&](int k0, int p) {
        bf16* Ad = smem + p * 4096;
        bf16* Bd = smem + 8192 + p * 2048;
        gll16(A + (size_t)(row0 + wave * 32 + srow) * ND + k0 + scol, Ad + (wave * 32) * 32);
        gll16(A + (size_t)(row0 + wave * 32 + 16 + srow) * ND + k0 + scol, Ad + (wave * 32 + 16) * 32);
        gll16(Bm + (size_t)(col0 + wave * 16 + srow) * ND + k0 + scol, Bd + (wave * 16) * 32);
    };

    stage(0, 0);
    __syncthreads();
    for (int k0 = 0; k0 < ND; k0 += 32) {
        const int p = (k0 >> 5) & 1;
        if (k0 + 32 < ND) stage(k0 + 32, p ^ 1);
        const bf16* As = smem + p * 4096;
        const bf16* Bs = smem + 8192 + p * 2048;
        bf16x8 af[4], bff[2];
        #pragma unroll
        for (int t = 0; t < 4; ++t)
            af[t] = *(const bf16x8*)(As + (wr + t * 16 + l15) * 32 + quad * 8);
        #pragma unroll
        for (int t = 0; t < 2; ++t)
            bff[t] = *(const bf16x8*)(Bs + (wc + t * 16 + l15) * 32 + quad * 8);
        #pragma unroll
        for (int mt = 0; mt < 4; ++mt)
            #pragma unroll
            for (int nt = 0; nt < 2; ++nt)
                acc[mt][nt] = mfma16(af[mt], bff[nt], acc[mt][nt]);
        __syncthreads();
    }

    #pragma unroll
    for (int nt = 0; nt < 2; ++nt) {
        int col = col0 + wc + nt * 16 + l15;
        float bv = bias[col];
        #pragma unroll
        for (int mt = 0; mt < 4; ++mt) {
            int row = row0 + wr + mt * 16 + quad * 4;
            #pragma unroll
            for (int r = 0; r < 4; ++r)
                C[(size_t)(row + r) * ND + col] = acc[mt][nt][r] + bv;
        }
    }
}

// ---------------- flash attention (R13): hoisted frags, 2-waves/EU reg budget ----------------
__global__ __launch_bounds__(256) __attribute__((amdgpu_waves_per_eu(2, 2)))
void attn(const bf16* __restrict__ Q,
          const bf16* __restrict__ K,
          const bf16* __restrict__ Vf,
          bf16* __restrict__ Y) {
    __shared__ bf16 Ksm[2][8192];
    __shared__ bf16 Vsm[2][8192];
    int bid = blockIdx.x;
    int g = bid >> 5;
    int bh = bid & 31;
    int qt = (g < 8) ? (15 - g) : (g - 8);
    int tid = threadIdx.x;
    int wave = tid >> 6, lane = tid & 63;
    int quad = lane >> 4, l15 = lane & 15;
    int q0 = qt * 128 + wave * 32;
    const bf16* Qh = Q + (size_t)bh * NS * 64;
    const bf16* Kh = K + (size_t)bh * NS * 64;
    const float NEG_INF = -__builtin_inff();

    const int krow = wave * 8 + (lane >> 3);
    const int ksx  = (lane & 7) ^ (krow & 7);
    const bf16* sK = Kh + (size_t)krow * 64 + ksx * 8;
    const bf16* sV = Vf + (size_t)bh * 131072 + wave * 2048 + lane * 8;

    const bf16* pk0 = &Ksm[0][l15 * 64 + ((quad) ^ (l15 & 7)) * 8];
    const bf16* pk1 = &Ksm[0][l15 * 64 + ((4 + quad) ^ (l15 & 7)) * 8];
    const bf16* pvf = &Vsm[0][lane * 8];

    bf16x8 bq[2][2];
    #pragma unroll
    for (int t = 0; t < 2; ++t)
        #pragma unroll
        for (int hh = 0; hh < 2; ++hh)
            bq[t][hh] = *(const bf16x8*)(Qh + (size_t)(q0 + t * 16 + l15) * 64 + hh * 32 + quad * 8);

    f32x4 o[2][4] = {};
    float lsum[2] = {0.f, 0.f};

    auto stage = [&](int c, int par) {
        const int kb = c * 128;
        bf16* dK = &Ksm[par][wave * 512];
        bf16* dV = &Vsm[par][wave * 2048];
        #pragma unroll
        for (int i = 0; i < 4; ++i)
            gll16(sK + (size_t)(kb + i * 32) * 64, dK + i * 2048);
        #pragma unroll
        for (int nt = 0; nt < 4; ++nt)
            gll16(sV + (size_t)(kb >> 5) * 2048 + nt * 512, dV + nt * 512);
    };

    auto compute = [&](int cc, int par) {
        const int kb = cc * 128;
        const int pb = par * 8192;
        bf16x8 ak[4][4], vf[4][4];
        #pragma unroll
        for (int ksub = 0; ksub < 4; ++ksub) {
            ak[ksub][0] = *(const bf16x8*)(pk0 + pb + ksub * 2048);
            ak[ksub][1] = *(const bf16x8*)(pk1 + pb + ksub * 2048);
            ak[ksub][2] = *(const bf16x8*)(pk0 + pb + ksub * 2048 + 1024);
            ak[ksub][3] = *(const bf16x8*)(pk1 + pb + ksub * 2048 + 1024);
            vf[ksub][0] = *(const bf16x8*)(pvf + pb + ksub * 2048);
            vf[ksub][1] = *(const bf16x8*)(pvf + pb + ksub * 2048 + 512);
            vf[ksub][2] = *(const bf16x8*)(pvf + pb + ksub * 2048 + 1024);
            vf[ksub][3] = *(const bf16x8*)(pvf + pb + ksub * 2048 + 1536);
        }
        #pragma unroll
        for (int ksub = 0; ksub < 4; ++ksub) {
            const int kbs = kb + ksub * 32;
            if (kbs <= q0) {
                const bool masked = (kbs == q0);
                #pragma unroll
                for (int t = 0; t < 2; ++t) {
                    f32x4 sh0 = {}, sh1 = {};
                    sh0 = mfma16(ak[ksub][0], bq[t][0], sh0);
                    sh0 = mfma16(ak[ksub][1], bq[t][1], sh0);
                    sh1 = mfma16(ak[ksub][2], bq[t][0], sh1);
                    sh1 = mfma16(ak[ksub][3], bq[t][1], sh1);
                    if (masked) {
                        int qy = q0 + t * 16 + l15;
                        #pragma unroll
                        for (int r = 0; r < 4; ++r) {
                            if (kbs + quad * 4 + r > qy)      sh0[r] = NEG_INF;
                            if (kbs + 16 + quad * 4 + r > qy) sh1[r] = NEG_INF;
                        }
                    }
                    bf16x8 pa;
                    float ls = 0.f;
                    #pragma unroll
                    for (int j = 0; j < 4; ++j) {
                        float p0 = __expf(sh0[j]);
                        float p1 = __expf(sh1[j]);
                        ls += p0 + p1;
                        pa[j] = (bf16)p0;
                        pa[4 + j] = (bf16)p1;
                    }
                    lsum[t] += ls;
                    o[t][0] = mfma16(pa, vf[ksub][0], o[t][0]);
                    o[t][1] = mfma16(pa, vf[ksub][1], o[t][1]);
                    o[t][2] = mfma16(pa, vf[ksub][2], o[t][2]);
                    o[t][3] = mfma16(pa, vf[ksub][3], o[t][3]);
                }
            }
        }
    };

    const int ncb = qt + 1;
    stage(0, 0);
    __syncthreads();
    for (int c = 0; c < ncb; ++c) {
        const int par = c & 1;
        if (c + 1 < ncb) stage(c + 1, par ^ 1);
        compute(c, par);
        __syncthreads();
    }

    int b = bh >> 4, h = bh & 15;
    bf16* ep = &Ksm[0][wave * 2048];
    #pragma unroll
    for (int t = 0; t < 2; ++t) {
        float red = lsum[t];
        red += __shfl_xor(red, 16);
        red += __shfl_xor(red, 32);
        #pragma unroll
        for (int r = 0; r < 4; ++r) {
            float il = 1.0f / __shfl(red, quad * 4 + r);
            #pragma unroll
            for (int nt = 0; nt < 4; ++nt)
                ep[(t * 16 + quad * 4 + r) * 64 + nt * 16 + l15] = (bf16)(o[t][nt][r] * il);
        }
    }
    asm volatile("s_waitcnt lgkmcnt(0)" ::: "memory");
    bf16* gbase = Y + ((size_t)(b * NS + q0 + (lane >> 3)) << 10) + h * 64 + (lane & 7) * 8;
    const bf16* lbase = ep + (lane >> 3) * 64 + (lane & 7) * 8;
    #pragma unroll
    for (int i = 0; i < 4; ++i) {
        bf16x8 v8 = *(const bf16x8*)(lbase + i * 512);
        *(bf16x8*)(gbase + ((size_t)i * 8 << 10)) = v8;
    }
}

// ---------------- host launch ----------------
extern "C" void kernel_launch(void* const* d_in, const int* in_sizes, int n_in,
                              void* d_out, int out_size, void* d_ws, size_t ws_size,
                              hipStream_t stream) {
    const float* x      = (const float*)d_in[0];
    const float* norm_w = (const float*)d_in[1];
    const float* qkv_w  = (const float*)d_in[2];
    const float* qkv_b  = (const float*)d_in[3];
    const float* proj_w = (const float*)d_in[4];
    const float* proj_b = (const float*)d_in[5];
    float* out = (float*)d_out;

    char* ws = (char*)d_ws;
    size_t off = 0;
    bf16* xn    = (bf16*)(ws + off); off += (size_t)ROWS * ND * 2;
    bf16* wq    = (bf16*)(ws + off); off += (size_t)E3 * ND * 2;
    bf16* wp    = (bf16*)(ws + off); off += (size_t)ND * ND * 2;   // contiguous after wq
    bf16* Qb    = (bf16*)(ws + off); off += (size_t)NB * NH * NS * HD * 2;
    bf16* Kb    = (bf16*)(ws + off); off += (size_t)NB * NH * NS * HD * 2;
    bf16* Vfrag = (bf16*)(ws + off); off += (size_t)NB * NH * HD * NS * 2;
    bf16* Y     = (bf16*)(ws + off); off += (size_t)ROWS * ND * 2;
    float4* tab = (float4*)(ws + off); off += (size_t)NS * 16 * sizeof(float4);

    prep<<<8320, 256, 0, stream>>>(qkv_w, proj_w, x, norm_w, wq, xn, tab);
    gemm_qkv_rope<<<dim3(ROWS / 128, E3 / 128), 256, 0, stream>>>(xn, wq, qkv_b, tab, Qb, Kb, Vfrag);
    attn<<<NB * NH * (NS / 128), 256, 0, stream>>>(Qb, Kb, Vfrag, Y);
    gemm_proj<<<dim3(ROWS / 128, ND / 64), 256, 0, stream>>>(Y, wp, proj_b, out);
}